// Round 3
// baseline (20103.548 us; speedup 1.0000x reference)
//
#include <hip/hip_runtime.h>
#include <hip/hip_bf16.h>
#include <hip/hip_fp16.h>

// ---------------------------------------------------------------------------
// POSTagger: char-CNN -> concat(word emb) -> xg GEMM -> sequential LSTM (the
// bottleneck, single workgroup / one CU) -> dense + log_softmax.
// Sizes: S=4096, LC=16, CDIM=10, F=32, WDIM=250, H=250, 4H=1000,
//        K=F+WDIM=282, TAGS=50.
// ---------------------------------------------------------------------------

typedef _Float16 h2 __attribute__((ext_vector_type(2)));

__device__ __forceinline__ float dot2(unsigned int w, unsigned int h, float acc) {
#if __has_builtin(__builtin_amdgcn_fdot2)
    return __builtin_amdgcn_fdot2(__builtin_bit_cast(h2, w),
                                  __builtin_bit_cast(h2, h), acc, false);
#else
    h2 a = __builtin_bit_cast(h2, w), b = __builtin_bit_cast(h2, h);
    return acc + (float)a[0] * (float)b[0] + (float)a[1] * (float)b[1];
#endif
}

// sum over the 4 lanes of a quad via DPP quad_perm (all lanes get the total)
__device__ __forceinline__ float quad_sum(float v) {
    int x = __builtin_bit_cast(int, v);
    int y = __builtin_amdgcn_update_dpp(x, x, 0xB1, 0xF, 0xF, false); // [1,0,3,2]
    v += __builtin_bit_cast(float, y);
    x = __builtin_bit_cast(int, v);
    y = __builtin_amdgcn_update_dpp(x, x, 0x4E, 0xF, 0xF, false);     // [2,3,0,1]
    v += __builtin_bit_cast(float, y);
    return v;
}

// ---------------------------------------------------------------------------
// K0: pack W_hh to f16 for the split-K layout.
// Thread tid of K3: q=tid>>2, kc=tid&3; handles rows 4q+m (m=0..3), pairs
// p = 32*kc + 4*j + c (j=0..7, c=0..3), elements 2p,2p+1 (zero if >=250 or
// row>=1000).
//   wpackC [3*8*1024] uint4 : slot (m*8+j)*1024+tid  (rows m=0..2, registers)
//   wpackD [8*1024]   uint4 : slot j*1024+tid        (row  m=3, LDS)
// ---------------------------------------------------------------------------
__global__ void prep_kernel(const float* __restrict__ whh,  // [1000][250]
                            uint4* __restrict__ wpackC,
                            uint4* __restrict__ wpackD) {
    int id = blockIdx.x * 256 + threadIdx.x;      // 0..32767
    if (id >= 32768) return;
    bool isC = id < 24576;
    int rel = isC ? id : id - 24576;
    int tid = rel & 1023;
    int j = (rel >> 10) & 7;
    int m = isC ? (rel >> 13) : 3;
    int q = tid >> 2, kc = tid & 3;
    int row = 4 * q + m;
    unsigned ww[4];
#pragma unroll
    for (int c = 0; c < 4; ++c) {
        int p = 32 * kc + 4 * j + c;
        float e0 = (row < 1000 && 2 * p < 250) ? whh[row * 250 + 2 * p] : 0.0f;
        float e1 = (row < 1000 && 2 * p + 1 < 250) ? whh[row * 250 + 2 * p + 1] : 0.0f;
        h2 hp; hp[0] = (_Float16)e0; hp[1] = (_Float16)e1;
        ww[c] = __builtin_bit_cast(unsigned, hp);
    }
    uint4 v; v.x = ww[0]; v.y = ww[1]; v.z = ww[2]; v.w = ww[3];
    if (isC) wpackC[rel] = v; else wpackD[rel] = v;
}

// ---------------------------------------------------------------------------
// K1: xT[282][4096]: rows 0..31 = char-CNN features^T (conv3 pad1 + bias +
// max over time), rows 32..281 = gathered word embeddings^T. 64 words/block.
// ---------------------------------------------------------------------------
__global__ __launch_bounds__(256) void build_xt(
    const int* __restrict__ ci, const int* __restrict__ wi,
    const float* __restrict__ cemb, const float* __restrict__ wemb,
    const float* __restrict__ convw, const float* __restrict__ convb,
    float* __restrict__ xT) {
    __shared__ float ce[64][16][10];
    __shared__ float cw[32][30];
    __shared__ float cb[32];
    __shared__ int widx[64];
    const int tid = threadIdx.x;
    const int w0 = blockIdx.x * 64;

    for (int i = tid; i < 960; i += 256) cw[i / 30][i % 30] = convw[i];
    if (tid < 32) cb[tid] = convb[tid];
    if (tid < 64) widx[tid] = wi[w0 + tid];
    for (int i = tid; i < 1024; i += 256) {
        int w = i >> 4, lc = i & 15;
        int idx = ci[(w0 + w) * 16 + lc];
#pragma unroll
        for (int c = 0; c < 10; ++c) ce[w][lc][c] = cemb[idx * 10 + c];
    }
    __syncthreads();

    for (int i = tid; i < 2048; i += 256) {
        int w = i >> 5, f = i & 31;
        float mx = -1e30f;
        for (int t = 0; t < 16; ++t) {
            float s = cb[f];
#pragma unroll
            for (int dt = 0; dt < 3; ++dt) {
                int tt = t + dt - 1;
                if (tt >= 0 && tt < 16) {
#pragma unroll
                    for (int c = 0; c < 10; ++c)
                        s += ce[w][tt][c] * cw[f][c * 3 + dt];
                }
            }
            mx = fmaxf(mx, s);
        }
        xT[f * 4096 + w0 + w] = mx;
    }
    for (int i = tid; i < 64 * 250; i += 256) {
        int w = i & 63, jj = i >> 6;
        xT[(32 + jj) * 4096 + w0 + w] = wemb[(long)widx[w] * 250 + jj];
    }
}

// ---------------------------------------------------------------------------
// K2: xg[4096][1000] = x @ W_ih^T + (b_ih + b_hh).
// ---------------------------------------------------------------------------
__global__ __launch_bounds__(256) void xg_gemm(
    const float* __restrict__ wih,  // [1000][282]
    const float* __restrict__ xT,   // [282][4096]
    const float* __restrict__ bih, const float* __restrict__ bhh,
    float* __restrict__ xg) {       // [4096][1000]
    const int g = blockIdx.y * 256 + threadIdx.x;
    const int gg = (g < 1000) ? g : 999;
    const int w0 = blockIdx.x * 16;
    float acc[16];
#pragma unroll
    for (int i = 0; i < 16; ++i) acc[i] = 0.0f;
    const float* wrow = wih + gg * 282;
    for (int k = 0; k < 282; ++k) {
        float wv = wrow[k];
        const float* xrow = xT + k * 4096 + w0;
#pragma unroll
        for (int i = 0; i < 16; ++i) acc[i] = fmaf(wv, xrow[i], acc[i]);
    }
    if (g < 1000) {
        float b = bih[g] + bhh[g];
#pragma unroll
        for (int i = 0; i < 16; ++i) xg[(w0 + i) * 1000 + g] = acc[i] + b;
    }
}

// ---------------------------------------------------------------------------
// K3: sequential LSTM, single block of 1024 (16 waves), 4-way split-K.
//  - quad q owns rows 4q..4q+3; lane kc covers pairs [32kc, 32kc+32).
//  - rows m=0..2 weights in 96 VGPRs; row m=3 from XOR-swizzled LDS
//    (8-way bank spread = full LDS BW).
//  - h broadcast: f16 pairs in a FRESH 512B global slot per step (plain
//    vector stores + __syncthreads ordering; vL1 can't be stale on a
//    never-before-loaded line). Consumers read their 128B chunk as 8x dwordx4.
//  - quad all-reduce via DPP; lane kc keeps row tid (=4q+kc); + xg[tid].
//  - gate rows: i=0..249, f=250..499, g=500..749 (tanh), o=750..999.
// ---------------------------------------------------------------------------
__global__ __launch_bounds__(1024) void lstm_scan(
    const uint4* __restrict__ wpackC,
    const uint4* __restrict__ wpackD,
    const float* __restrict__ xg,     // [4096][1000]
    unsigned* __restrict__ hslots,    // [4097][128] f16-pair slots (512B)
    float* __restrict__ hsf32) {      // [4096][250]
    __shared__ uint4 lds_w3[8192];    // 128 KB
    __shared__ float lds_gates[1000]; // 4 KB

    const int tid = threadIdx.x;
    const int kc = tid & 3;
    const int sw = tid & 7;
    const bool rowv = (tid < 1000);

    // rows m=0..2 -> registers (coalesced loads)
    uint4 wq[3][8];
#pragma unroll
    for (int m = 0; m < 3; ++m)
#pragma unroll
        for (int j = 0; j < 8; ++j)
            wq[m][j] = wpackC[(m * 8 + j) * 1024 + tid];
    // row m=3 -> swizzled LDS (private 128B per thread, 8-way bank spread)
#pragma unroll
    for (int j = 0; j < 8; ++j)
        lds_w3[(tid << 3) | (j ^ sw)] = wpackD[j * 1024 + tid];

    if (tid < 128) hslots[tid] = 0u;   // h_{-1} = 0 (incl pad pairs)
    float cc0 = 0.0f, cc1 = 0.0f;
    __syncthreads();

    const int rtid = rowv ? tid : 999;
    float xg_cur = xg[rtid];           // t = 0
    const bool isg = (tid >= 500) & (tid < 750);

#pragma unroll 1
    for (int t = 0; t < 4096; ++t) {
        const unsigned* hsl = hslots + (t << 7);
        const int tn = (t + 1 < 4096) ? t + 1 : 4095;
        float xg_nxt = xg[tn * 1000 + rtid];

        float a0 = 0.0f, a1 = 0.0f, a2 = 0.0f, a3 = 0.0f;
#define DOT_J(J)                                                            \
        {                                                                   \
            uint4 hj = *(const uint4*)(hsl + (kc << 5) + ((J) << 2));       \
            uint4 w3 = lds_w3[(tid << 3) | ((J) ^ sw)];                     \
            a0 = dot2(wq[0][J].x, hj.x, a0); a0 = dot2(wq[0][J].y, hj.y, a0);\
            a0 = dot2(wq[0][J].z, hj.z, a0); a0 = dot2(wq[0][J].w, hj.w, a0);\
            a1 = dot2(wq[1][J].x, hj.x, a1); a1 = dot2(wq[1][J].y, hj.y, a1);\
            a1 = dot2(wq[1][J].z, hj.z, a1); a1 = dot2(wq[1][J].w, hj.w, a1);\
            a2 = dot2(wq[2][J].x, hj.x, a2); a2 = dot2(wq[2][J].y, hj.y, a2);\
            a2 = dot2(wq[2][J].z, hj.z, a2); a2 = dot2(wq[2][J].w, hj.w, a2);\
            a3 = dot2(w3.x, hj.x, a3); a3 = dot2(w3.y, hj.y, a3);           \
            a3 = dot2(w3.z, hj.z, a3); a3 = dot2(w3.w, hj.w, a3);           \
        }
        DOT_J(0) DOT_J(1) DOT_J(2) DOT_J(3)
        DOT_J(4) DOT_J(5) DOT_J(6) DOT_J(7)
#undef DOT_J

        a0 = quad_sum(a0); a1 = quad_sum(a1);
        a2 = quad_sum(a2); a3 = quad_sum(a3);
        float av = (kc == 0) ? a0 : (kc == 1) ? a1 : (kc == 2) ? a2 : a3;
        av += xg_cur;

        // sigmoid for i,f,o; tanh for g: tanh(x) = 1 - 2/(e^{2x}+1)
        {
            float e = __expf(isg ? 2.0f * av : -av);
            float s = 1.0f / (1.0f + e);
            float act = isg ? (1.0f - 2.0f * s) : s;
            if (rowv) lds_gates[tid] = act;
        }
        __syncthreads();

        if (tid < 125) {
            float2 gi = *(const float2*)&lds_gates[2 * tid];
            float2 gf = *(const float2*)&lds_gates[250 + 2 * tid];
            float2 gg = *(const float2*)&lds_gates[500 + 2 * tid];
            float2 go = *(const float2*)&lds_gates[750 + 2 * tid];
            cc0 = fmaf(gf.x, cc0, gi.x * gg.x);
            cc1 = fmaf(gf.y, cc1, gi.y * gg.y);
            float h0 = go.x * tanhf(cc0);
            float h1 = go.y * tanhf(cc1);
            *(float2*)&hsf32[t * 250 + 2 * tid] = make_float2(h0, h1);
            h2 hp; hp[0] = (_Float16)h0; hp[1] = (_Float16)h1;
            hslots[((t + 1) << 7) + tid] = __builtin_bit_cast(unsigned, hp);
        } else if (tid < 128) {
            hslots[((t + 1) << 7) + tid] = 0u;   // keep pad pairs zero
        }
        __syncthreads();   // stores drained (vmcnt 0) before next step's loads
        xg_cur = xg_nxt;
    }
}

// ---------------------------------------------------------------------------
// K4: logits = hs @ dense_w^T + dense_b; out = log_softmax rows.
// ---------------------------------------------------------------------------
__global__ __launch_bounds__(256) void dense_lsm(
    const float* __restrict__ hs, const float* __restrict__ dw,
    const float* __restrict__ db, float* __restrict__ out) {
    const int wave = threadIdx.x >> 6, lane = threadIdx.x & 63;
    const int s = blockIdx.x * 4 + wave;
    const int tag = lane;
    float acc = -1e30f;
    if (tag < 50) {
        acc = db[tag];
        const float* h = hs + (long)s * 250;
        const float* wrow = dw + tag * 250;
        for (int k = 0; k < 250; ++k) acc = fmaf(h[k], wrow[k], acc);
    }
    float m = acc;
#pragma unroll
    for (int off = 32; off; off >>= 1) m = fmaxf(m, __shfl_xor(m, off));
    float e = (tag < 50) ? expf(acc - m) : 0.0f;
    float ssum = e;
#pragma unroll
    for (int off = 32; off; off >>= 1) ssum += __shfl_xor(ssum, off);
    if (tag < 50) out[(long)s * 50 + tag] = acc - m - logf(ssum);
}

// ---------------------------------------------------------------------------
// launch. ws layout (23.1 MB; xT aliases hslots+hsf32 — disjoint live ranges):
//   [wpackC 393216][wpackD 131072][xg 16384000][hslots 2097664][hsf32 4096000]
// ---------------------------------------------------------------------------
extern "C" void kernel_launch(void* const* d_in, const int* in_sizes, int n_in,
                              void* d_out, int out_size, void* d_ws, size_t ws_size,
                              hipStream_t stream) {
    const int*   ci    = (const int*)d_in[0];
    const int*   wi    = (const int*)d_in[1];
    const float* cemb  = (const float*)d_in[2];
    const float* wemb  = (const float*)d_in[3];
    const float* convw = (const float*)d_in[4];
    const float* convb = (const float*)d_in[5];
    const float* wih   = (const float*)d_in[6];
    const float* whh   = (const float*)d_in[7];
    const float* bih   = (const float*)d_in[8];
    const float* bhh   = (const float*)d_in[9];
    const float* dw    = (const float*)d_in[10];
    const float* db    = (const float*)d_in[11];
    float* out = (float*)d_out;

    char* ws = (char*)d_ws;
    constexpr size_t OFF_WPC   = 0;          // 393,216
    constexpr size_t OFF_WPD   = 393216;     // 131,072
    constexpr size_t OFF_XG    = 524288;     // 16,384,000
    constexpr size_t OFF_HSL   = 16908288;   // 2,097,664
    constexpr size_t OFF_HSF   = 19005952;   // 4,096,000 -> end 23,101,952
    constexpr size_t OFF_XT    = OFF_HSL;    // alias: xT (4,620,288) dead after K2

    uint4*    wpackC = (uint4*)(ws + OFF_WPC);
    uint4*    wpackD = (uint4*)(ws + OFF_WPD);
    float*    xg     = (float*)(ws + OFF_XG);
    unsigned* hslots = (unsigned*)(ws + OFF_HSL);
    float*    hsf32  = (float*)(ws + OFF_HSF);
    float*    xT     = (float*)(ws + OFF_XT);

    prep_kernel<<<dim3(128), dim3(256), 0, stream>>>(whh, wpackC, wpackD);
    build_xt<<<dim3(64), dim3(256), 0, stream>>>(ci, wi, cemb, wemb, convw,
                                                 convb, xT);
    xg_gemm<<<dim3(256, 4), dim3(256), 0, stream>>>(wih, xT, bih, bhh, xg);
    lstm_scan<<<dim3(1), dim3(1024), 0, stream>>>(wpackC, wpackD, xg, hslots,
                                                  hsf32);
    dense_lsm<<<dim3(1024), dim3(256), 0, stream>>>(hsf32, dw, db, out);
}

// Round 4
// 11920.490 us; speedup vs baseline: 1.6865x; 1.6865x over previous
//
#include <hip/hip_runtime.h>
#include <hip/hip_bf16.h>
#include <hip/hip_fp16.h>

// ---------------------------------------------------------------------------
// POSTagger: char-CNN -> concat(word emb) -> xg GEMM -> sequential LSTM (the
// bottleneck, single workgroup / one CU) -> dense + log_softmax.
// Sizes: S=4096, LC=16, CDIM=10, F=32, WDIM=250, H=250, 4H=1000,
//        K=F+WDIM=282, TAGS=50.
//
// LSTM design (round 4): 512 threads / 8 waves. Thread tid owns gate-rows
// 2*tid and 2*tid+1 with ALL 128 f16 weight-pairs per row in VGPRs
// (64 uint4 = 256 VGPRs; __launch_bounds__(512,2) caps alloc at 512 -> no
// spill). h_{t-1} lives in LDS as 128 packed f16 pairs; every lane reads the
// same address per ds_read_b128 -> pure broadcast, conflict-free.
// ---------------------------------------------------------------------------

typedef _Float16 h2 __attribute__((ext_vector_type(2)));

__device__ __forceinline__ float dot2(unsigned int w, unsigned int h, float acc) {
#if __has_builtin(__builtin_amdgcn_fdot2)
    return __builtin_amdgcn_fdot2(__builtin_bit_cast(h2, w),
                                  __builtin_bit_cast(h2, h), acc, false);
#else
    h2 a = __builtin_bit_cast(h2, w), b = __builtin_bit_cast(h2, h);
    return acc + (float)a[0] * (float)b[0] + (float)a[1] * (float)b[1];
#endif
}

// ---------------------------------------------------------------------------
// K0: pack W_hh into the per-thread-register layout of K3.
// wpackE[((m*8+J)*4+u)*512 + tid] = uint4 of f16 pairs p = J*16+u*4+{0..3}
// of row (2*tid+m); elements 2p,2p+1 (zero when >=250 or row>=1000).
// 32768 uint4 = 512 KB.
// ---------------------------------------------------------------------------
__global__ void prep_kernel(const float* __restrict__ whh,  // [1000][250]
                            uint4* __restrict__ wpackE) {
    int id = blockIdx.x * 256 + threadIdx.x;      // 0..32767
    if (id >= 32768) return;
    int tid = id & 511;
    int rest = id >> 9;          // 0..63
    int u = rest & 3, J = (rest >> 2) & 7, m = rest >> 5;
    int row = 2 * tid + m;
    unsigned ww[4];
#pragma unroll
    for (int c = 0; c < 4; ++c) {
        int p = J * 16 + u * 4 + c;
        float e0 = (row < 1000 && 2 * p < 250) ? whh[row * 250 + 2 * p] : 0.0f;
        float e1 = (row < 1000 && 2 * p + 1 < 250) ? whh[row * 250 + 2 * p + 1] : 0.0f;
        h2 hp; hp[0] = (_Float16)e0; hp[1] = (_Float16)e1;
        ww[c] = __builtin_bit_cast(unsigned, hp);
    }
    uint4 v; v.x = ww[0]; v.y = ww[1]; v.z = ww[2]; v.w = ww[3];
    wpackE[rest * 512 + tid] = v;
}

// ---------------------------------------------------------------------------
// K1: xT[282][4096]: rows 0..31 = char-CNN features^T (conv3 pad1 + bias +
// max over time), rows 32..281 = gathered word embeddings^T. 64 words/block.
// ---------------------------------------------------------------------------
__global__ __launch_bounds__(256) void build_xt(
    const int* __restrict__ ci, const int* __restrict__ wi,
    const float* __restrict__ cemb, const float* __restrict__ wemb,
    const float* __restrict__ convw, const float* __restrict__ convb,
    float* __restrict__ xT) {
    __shared__ float ce[64][16][10];
    __shared__ float cw[32][30];
    __shared__ float cb[32];
    __shared__ int widx[64];
    const int tid = threadIdx.x;
    const int w0 = blockIdx.x * 64;

    for (int i = tid; i < 960; i += 256) cw[i / 30][i % 30] = convw[i];
    if (tid < 32) cb[tid] = convb[tid];
    if (tid < 64) widx[tid] = wi[w0 + tid];
    for (int i = tid; i < 1024; i += 256) {
        int w = i >> 4, lc = i & 15;
        int idx = ci[(w0 + w) * 16 + lc];
#pragma unroll
        for (int c = 0; c < 10; ++c) ce[w][lc][c] = cemb[idx * 10 + c];
    }
    __syncthreads();

    for (int i = tid; i < 2048; i += 256) {
        int w = i >> 5, f = i & 31;
        float mx = -1e30f;
        for (int t = 0; t < 16; ++t) {
            float s = cb[f];
#pragma unroll
            for (int dt = 0; dt < 3; ++dt) {
                int tt = t + dt - 1;
                if (tt >= 0 && tt < 16) {
#pragma unroll
                    for (int c = 0; c < 10; ++c)
                        s += ce[w][tt][c] * cw[f][c * 3 + dt];
                }
            }
            mx = fmaxf(mx, s);
        }
        xT[f * 4096 + w0 + w] = mx;
    }
    for (int i = tid; i < 64 * 250; i += 256) {
        int w = i & 63, jj = i >> 6;
        xT[(32 + jj) * 4096 + w0 + w] = wemb[(long)widx[w] * 250 + jj];
    }
}

// ---------------------------------------------------------------------------
// K2: xg[4096][1000] = x @ W_ih^T + (b_ih + b_hh).
// ---------------------------------------------------------------------------
__global__ __launch_bounds__(256) void xg_gemm(
    const float* __restrict__ wih,  // [1000][282]
    const float* __restrict__ xT,   // [282][4096]
    const float* __restrict__ bih, const float* __restrict__ bhh,
    float* __restrict__ xg) {       // [4096][1000]
    const int g = blockIdx.y * 256 + threadIdx.x;
    const int gg = (g < 1000) ? g : 999;
    const int w0 = blockIdx.x * 16;
    float acc[16];
#pragma unroll
    for (int i = 0; i < 16; ++i) acc[i] = 0.0f;
    const float* wrow = wih + gg * 282;
    for (int k = 0; k < 282; ++k) {
        float wv = wrow[k];
        const float* xrow = xT + k * 4096 + w0;
#pragma unroll
        for (int i = 0; i < 16; ++i) acc[i] = fmaf(wv, xrow[i], acc[i]);
    }
    if (g < 1000) {
        float b = bih[g] + bhh[g];
#pragma unroll
        for (int i = 0; i < 16; ++i) xg[(w0 + i) * 1000 + g] = acc[i] + b;
    }
}

// ---------------------------------------------------------------------------
// K3: sequential LSTM. One block, 512 threads (8 waves), one CU.
// Gate rows: i=0..249, f=250..499, g=500..749 (tanh), o=750..999.
// Row pair (2tid, 2tid+1) never straddles a gate boundary (boundaries even).
// ---------------------------------------------------------------------------
__global__ __launch_bounds__(512, 2) void lstm_scan(
    const uint4* __restrict__ wpackE,  // [64][512]
    const float* __restrict__ xg,      // [4096][1000]
    float* __restrict__ hsf32) {       // [4096][250]
    __shared__ unsigned lds_h[128];    // h_{t-1}: f16 pair p at dword p
    __shared__ float lds_gates[1000];

    const int tid = threadIdx.x;
    const bool act_on = (tid < 500);
    const int row0 = act_on ? 2 * tid : 996;   // clamped for safe loads
    const bool isg = (tid >= 250) & (tid < 375);   // rows 500..749

    // 64 uint4 of weights -> registers (all indices compile-time constant)
    uint4 wq[2][8][4];
#pragma unroll
    for (int m = 0; m < 2; ++m)
#pragma unroll
        for (int J = 0; J < 8; ++J)
#pragma unroll
            for (int u = 0; u < 4; ++u)
                wq[m][J][u] = wpackE[((m * 8 + J) * 4 + u) * 512 + tid];

    if (tid < 128) lds_h[tid] = 0u;    // h_{-1} = 0 (incl. pad pairs 125..127)
    float cc0 = 0.0f, cc1 = 0.0f;
    __syncthreads();

    float2 xg_cur = *(const float2*)&xg[row0];   // t = 0

#pragma unroll 1
    for (int t = 0; t < 4096; ++t) {
        const int tn = (t + 1 < 4096) ? t + 1 : 4095;
        float2 xg_nxt = *(const float2*)&xg[tn * 1000 + row0];

        float a0 = xg_cur.x, a1 = xg_cur.y;
#pragma unroll
        for (int J = 0; J < 8; ++J) {
            // all lanes read the same 16B -> LDS broadcast, conflict-free
            uint4 h0 = *(const uint4*)&lds_h[J * 16];
            uint4 h1 = *(const uint4*)&lds_h[J * 16 + 4];
            uint4 hx2 = *(const uint4*)&lds_h[J * 16 + 8];
            uint4 h3 = *(const uint4*)&lds_h[J * 16 + 12];
            a0 = dot2(wq[0][J][0].x, h0.x, a0); a0 = dot2(wq[0][J][0].y, h0.y, a0);
            a0 = dot2(wq[0][J][0].z, h0.z, a0); a0 = dot2(wq[0][J][0].w, h0.w, a0);
            a0 = dot2(wq[0][J][1].x, h1.x, a0); a0 = dot2(wq[0][J][1].y, h1.y, a0);
            a0 = dot2(wq[0][J][1].z, h1.z, a0); a0 = dot2(wq[0][J][1].w, h1.w, a0);
            a0 = dot2(wq[0][J][2].x, hx2.x, a0); a0 = dot2(wq[0][J][2].y, hx2.y, a0);
            a0 = dot2(wq[0][J][2].z, hx2.z, a0); a0 = dot2(wq[0][J][2].w, hx2.w, a0);
            a0 = dot2(wq[0][J][3].x, h3.x, a0); a0 = dot2(wq[0][J][3].y, h3.y, a0);
            a0 = dot2(wq[0][J][3].z, h3.z, a0); a0 = dot2(wq[0][J][3].w, h3.w, a0);
            a1 = dot2(wq[1][J][0].x, h0.x, a1); a1 = dot2(wq[1][J][0].y, h0.y, a1);
            a1 = dot2(wq[1][J][0].z, h0.z, a1); a1 = dot2(wq[1][J][0].w, h0.w, a1);
            a1 = dot2(wq[1][J][1].x, h1.x, a1); a1 = dot2(wq[1][J][1].y, h1.y, a1);
            a1 = dot2(wq[1][J][1].z, h1.z, a1); a1 = dot2(wq[1][J][1].w, h1.w, a1);
            a1 = dot2(wq[1][J][2].x, hx2.x, a1); a1 = dot2(wq[1][J][2].y, hx2.y, a1);
            a1 = dot2(wq[1][J][2].z, hx2.z, a1); a1 = dot2(wq[1][J][2].w, hx2.w, a1);
            a1 = dot2(wq[1][J][3].x, h3.x, a1); a1 = dot2(wq[1][J][3].y, h3.y, a1);
            a1 = dot2(wq[1][J][3].z, h3.z, a1); a1 = dot2(wq[1][J][3].w, h3.w, a1);
        }

        // activation: sigmoid for i,f,o rows; tanh for g rows.
        // tanh(x) = 1 - 2/(e^{2x}+1); sigmoid(x) = 1/(1+e^{-x})
        {
            float e0 = __expf(isg ? 2.0f * a0 : -a0);
            float e1 = __expf(isg ? 2.0f * a1 : -a1);
            float s0 = __builtin_amdgcn_rcpf(1.0f + e0);
            float s1 = __builtin_amdgcn_rcpf(1.0f + e1);
            float v0 = isg ? fmaf(-2.0f, s0, 1.0f) : s0;
            float v1 = isg ? fmaf(-2.0f, s1, 1.0f) : s1;
            if (act_on) *(float2*)&lds_gates[2 * tid] = make_float2(v0, v1);
        }
        __syncthreads();   // gates ready; all lds_h reads of this step done

        if (tid < 125) {
            float2 gi = *(const float2*)&lds_gates[2 * tid];
            float2 gf = *(const float2*)&lds_gates[250 + 2 * tid];
            float2 gg = *(const float2*)&lds_gates[500 + 2 * tid];
            float2 go = *(const float2*)&lds_gates[750 + 2 * tid];
            cc0 = fmaf(gf.x, cc0, gi.x * gg.x);
            cc1 = fmaf(gf.y, cc1, gi.y * gg.y);
            float e0 = __expf(2.0f * cc0), e1 = __expf(2.0f * cc1);
            float t0 = fmaf(-2.0f, __builtin_amdgcn_rcpf(1.0f + e0), 1.0f);
            float t1 = fmaf(-2.0f, __builtin_amdgcn_rcpf(1.0f + e1), 1.0f);
            float h0 = go.x * t0;
            float h1 = go.y * t1;
            *(float2*)&hsf32[t * 250 + 2 * tid] = make_float2(h0, h1);
            h2 hp; hp[0] = (_Float16)h0; hp[1] = (_Float16)h1;
            lds_h[tid] = __builtin_bit_cast(unsigned, hp);
        }
        __syncthreads();   // h_t visible to all before next step's reads
        xg_cur = xg_nxt;
    }
}

// ---------------------------------------------------------------------------
// K4: logits = hs @ dense_w^T + dense_b; out = log_softmax rows.
// ---------------------------------------------------------------------------
__global__ __launch_bounds__(256) void dense_lsm(
    const float* __restrict__ hs, const float* __restrict__ dw,
    const float* __restrict__ db, float* __restrict__ out) {
    const int wave = threadIdx.x >> 6, lane = threadIdx.x & 63;
    const int s = blockIdx.x * 4 + wave;
    const int tag = lane;
    float acc = -1e30f;
    if (tag < 50) {
        acc = db[tag];
        const float* h = hs + (long)s * 250;
        const float* wrow = dw + tag * 250;
        for (int k = 0; k < 250; ++k) acc = fmaf(h[k], wrow[k], acc);
    }
    float m = acc;
#pragma unroll
    for (int off = 32; off; off >>= 1) m = fmaxf(m, __shfl_xor(m, off));
    float e = (tag < 50) ? expf(acc - m) : 0.0f;
    float ssum = e;
#pragma unroll
    for (int off = 32; off; off >>= 1) ssum += __shfl_xor(ssum, off);
    if (tag < 50) out[(long)s * 50 + tag] = acc - m - logf(ssum);
}

// ---------------------------------------------------------------------------
// launch. ws layout (21.5 MB; xT aliases hsf32 region — xT dead after K2):
//   [wpackE 524288][xg 16384000][hsf32/xT max(4096000, 4620288)]
// ---------------------------------------------------------------------------
extern "C" void kernel_launch(void* const* d_in, const int* in_sizes, int n_in,
                              void* d_out, int out_size, void* d_ws, size_t ws_size,
                              hipStream_t stream) {
    const int*   ci    = (const int*)d_in[0];
    const int*   wi    = (const int*)d_in[1];
    const float* cemb  = (const float*)d_in[2];
    const float* wemb  = (const float*)d_in[3];
    const float* convw = (const float*)d_in[4];
    const float* convb = (const float*)d_in[5];
    const float* wih   = (const float*)d_in[6];
    const float* whh   = (const float*)d_in[7];
    const float* bih   = (const float*)d_in[8];
    const float* bhh   = (const float*)d_in[9];
    const float* dw    = (const float*)d_in[10];
    const float* db    = (const float*)d_in[11];
    float* out = (float*)d_out;

    char* ws = (char*)d_ws;
    constexpr size_t OFF_WPE = 0;          // 524,288
    constexpr size_t OFF_XG  = 524288;     // 16,384,000
    constexpr size_t OFF_HSF = 16908288;   // 4,620,288 (shared with xT)
    constexpr size_t OFF_XT  = OFF_HSF;

    uint4* wpackE = (uint4*)(ws + OFF_WPE);
    float* xg     = (float*)(ws + OFF_XG);
    float* hsf32  = (float*)(ws + OFF_HSF);
    float* xT     = (float*)(ws + OFF_XT);

    prep_kernel<<<dim3(128), dim3(256), 0, stream>>>(whh, wpackE);
    build_xt<<<dim3(64), dim3(256), 0, stream>>>(ci, wi, cemb, wemb, convw,
                                                 convb, xT);
    xg_gemm<<<dim3(256, 4), dim3(256), 0, stream>>>(wih, xT, bih, bhh, xg);
    lstm_scan<<<dim3(1), dim3(512), 0, stream>>>(wpackE, xg, hsf32);
    dense_lsm<<<dim3(1024), dim3(256), 0, stream>>>(hsf32, dw, db, out);
}